// Round 17
// baseline (338.417 us; speedup 1.0000x reference)
//
#include <hip/hip_runtime.h>
#include <math.h>

#define NV 4096      // variable nodes
#define MC 2048      // check nodes
#define DV 3
#define DC 6
#define NE (NV * DV) // 12288 edges
#define NB 2048      // batch
#define NITER 5
#define TPB 1024     // 16 waves/block; 2 blocks/CU -> 32 waves/CU (HW wave cap)

// Build per-check-node edge lists (slot order arbitrary due to atomics).
__global__ __launch_bounds__(256) void build_cn(const int* __restrict__ cn_idx,
                                                int* __restrict__ cn_edges,
                                                int* __restrict__ cn_cnt) {
    int e = blockIdx.x * 256 + threadIdx.x;
    if (e < NE) {
        int m = cn_idx[e];
        int slot = atomicAdd(&cn_cnt[m], 1);
        cn_edges[m * DC + slot] = e;
    }
}

// Sort each CN's 6 edges ascending (deterministic canonical order).
__global__ __launch_bounds__(256) void sort_cn(int* __restrict__ cn_edges) {
    int m = blockIdx.x * 256 + threadIdx.x;
    if (m < MC) {
        int v[DC];
        for (int j = 0; j < DC; ++j) v[j] = cn_edges[m * DC + j];
        for (int i = 1; i < DC; ++i) {
            int key = v[i]; int j = i - 1;
            while (j >= 0 && v[j] > key) { v[j + 1] = v[j]; --j; }
            v[j + 1] = key;
        }
        for (int j = 0; j < DC; ++j) cn_edges[m * DC + j] = v[j];
    }
}

// Bank-balance the slot assignment. In bp_iter, for fixed (c, j), one wave
// instruction reads msg[cn_edges[(w*64+l + 1024c)*6 + j]] across lanes
// l=0..63. The graph is block-invariant, so only 16 waves x 2 c-groups of
// address patterns exist. Greedily permute each CN's 6 edges across slots
// so every (group, slot) instruction spreads its 64 addresses evenly over
// the 32 LDS banks (bank = edge & 31). Reads are independent, writes carry
// per-edge values, sign parity is order-free; only P/M multiply order
// changes (float reassociation, ~ulp). In-place, row-local => race-free.
__global__ void balance_cn(int* __restrict__ cn_edges) {
    __shared__ int counts[16][DC][32];
    const int w = threadIdx.x;   // wave-in-block 0..15
    const int c = blockIdx.x;    // CN group 0..1
    for (int j = 0; j < DC; ++j)
        for (int k = 0; k < 32; ++k) counts[w][j][k] = 0;
    for (int l = 0; l < 64; ++l) {
        int* row = cn_edges + (w * 64 + l + c * TPB) * DC;
        int e[DC];
        for (int j = 0; j < DC; ++j) e[j] = row[j];
        unsigned used = 0;
        for (int j = 0; j < DC; ++j) {
            int best = 0, bestCnt = 1 << 30, bestE = 1 << 30;
            for (int q = 0; q < DC; ++q) {
                if (used & (1u << q)) continue;
                int cnt = counts[w][j][e[q] & 31];
                if (cnt < bestCnt || (cnt == bestCnt && e[q] < bestE)) {
                    bestCnt = cnt; best = q; bestE = e[q];
                }
            }
            used |= 1u << best;
            row[j] = e[best];
            counts[w][j][e[best] & 31]++;
        }
    }
}

// bare v_exp_f32 with -|x| folded as input modifier: u = 2^(-|x|)
static __device__ __forceinline__ float exp2_negabs(float x) {
    float r;
    asm volatile("v_exp_f32 %0, -abs(%1)" : "=v"(r) : "v"(x));
    return r;
}
// bare v_log_f32: log2(x)
static __device__ __forceinline__ float log2_raw(float x) {
    float r;
    asm volatile("v_log_f32 %0, %1" : "=v"(r) : "v"(x));
    return r;
}

// R15 structure (one sample/block, 48 KB edge-major LDS, two-phase barriers,
// (1024,8) -> 2 blocks/CU) + log2-domain messages (bare v_exp/v_log) +
// R13's bit-parity sign (no s[] array -> no spill). CN math [absmax 1.0
// proven R13-R15]:
//   u = 2^{-|mw2|}; a = 1+u; b = max(1-u, 1e-12)
//   P = PROD a; M = PROD b  (slot order = bank-balanced permutation)
//   val2_j = log2((P b_j + M a_j) / max(P b_j - M a_j, 2^-23 P b_j))
//            [den floor == ref clip at float32(1-1e-7) = 1-2^-23]
//   sign from bit parity (exact == ref mod-2); final out scaled by ln2.
__global__ __launch_bounds__(TPB, 8) void bp_iter(const float* __restrict__ noise_r,
                                                  const float* __restrict__ ew,
                                                  const int* __restrict__ cn_edges,
                                                  float* __restrict__ out) {
    __shared__ float msg[NE];
    const int b = blockIdx.x;
    const int t = threadIdx.x;

    const float NO    = (float)0.3981071705534972;         // 1/(R*2*10^(EbNo/10))
    const float NSTD  = sqrtf((float)(0.3981071705534972 * 0.5));
    const float LOG2E = 1.4426950408889634f;
    const float LN2   = 0.6931471805599453f;

    // Edge lists of this thread's 2 CNs (loop-invariant, bank-balanced slots).
    int idx[MC / TPB][DC];
#pragma unroll
    for (int c = 0; c < MC / TPB; ++c)
#pragma unroll
        for (int j = 0; j < DC; ++j)
            idx[c][j] = cn_edges[(t + TPB * c) * DC + j];

    float llr2[NV / TPB];   // log2-scaled channel LLRs
    const float* nb = noise_r + (size_t)b * NV;
#pragma unroll
    for (int k = 0; k < NV / TPB; ++k) {
        int n = t + TPB * k;
        float y  = 1.0f + NSTD * nb[n];
        float l2 = ((4.0f * y) / NO) * LOG2E;
        llr2[k] = l2;
        msg[3 * n + 0] = l2 * ew[3 * n + 0];
        msg[3 * n + 1] = l2 * ew[3 * n + 1];
        msg[3 * n + 2] = l2 * ew[3 * n + 2];
    }
    __syncthreads();

    for (int it = 0; it < NITER; ++it) {
        // ---- CN phase: each thread owns 2 check nodes ----
#pragma unroll
        for (int c = 0; c < MC / TPB; ++c) {
            float a[DC], bb[DC];
            unsigned spack = 0u;
#pragma unroll
            for (int j = 0; j < DC; ++j) {
                float mw = msg[idx[c][j]];
                spack |= ((__float_as_uint(mw) >> 31) & 1u) << j;
                float u = exp2_negabs(mw);          // 2^{-|mw2|} = e^{-|mw|}
                a[j]  = 1.0f + u;
                bb[j] = fmaxf(1.0f - u, 1e-12f);
            }
            const unsigned par = __popc(spack) & 1u;

            float P = 1.0f, M = 1.0f;
#pragma unroll
            for (int j = 0; j < DC; ++j) {
                P *= a[j];
                M *= bb[j];
            }

#pragma unroll
            for (int j = 0; j < DC; ++j) {
                float Pb  = P * bb[j];
                float Ma  = M * a[j];
                float num = Pb + Ma;
                float den = fmaxf(Pb - Ma, 0x1.0p-23f * Pb);   // == ref clip 1-2^-23
                float val = log2_raw(__fdividef(num, den));    // >= 0, log2 domain
                msg[idx[c][j]] = __uint_as_float(__float_as_uint(val) |
                                                 (((par ^ (spack >> j)) & 1u) << 31));
            }
        }
        __syncthreads();

        // ---- VN phase: each thread owns 4 variable nodes ----
        if (it < NITER - 1) {
#pragma unroll
            for (int k = 0; k < NV / TPB; ++k) {
                int n = t + TPB * k;
                float c0 = msg[3 * n + 0];
                float c1 = msg[3 * n + 1];
                float c2 = msg[3 * n + 2];
                float tot = llr2[k] + (c0 + c1 + c2);
                msg[3 * n + 0] = (tot - c0) * ew[3 * n + 0];
                msg[3 * n + 1] = (tot - c1) * ew[3 * n + 1];
                msg[3 * n + 2] = (tot - c2) * ew[3 * n + 2];
            }
            __syncthreads();
        } else {
#pragma unroll
            for (int k = 0; k < NV / TPB; ++k) {
                int n = t + TPB * k;
                float c0 = msg[3 * n + 0];
                float c1 = msg[3 * n + 1];
                float c2 = msg[3 * n + 2];
                out[(size_t)b * NV + n] = (llr2[k] + (c0 + c1 + c2)) * LN2;
            }
        }
    }
}

extern "C" void kernel_launch(void* const* d_in, const int* in_sizes, int n_in,
                              void* d_out, int out_size, void* d_ws, size_t ws_size,
                              hipStream_t stream) {
    const float* noise_r = (const float*)d_in[0];
    // d_in[1] = noise_i (unused by reference)
    const float* ew      = (const float*)d_in[2];
    // d_in[3] = vn_idx: known structure e // 3 (edges contiguous per VN)
    const int*   cn_idx  = (const int*)d_in[4];
    float* out = (float*)d_out;

    int* cn_edges = (int*)d_ws;        // NE ints
    int* cn_cnt   = cn_edges + NE;     // MC ints

    hipMemsetAsync(cn_cnt, 0, MC * sizeof(int), stream);
    build_cn<<<(NE + 255) / 256, 256, 0, stream>>>(cn_idx, cn_edges, cn_cnt);
    sort_cn<<<(MC + 255) / 256, 256, 0, stream>>>(cn_edges);
    balance_cn<<<MC / TPB, TPB / 64, 0, stream>>>(cn_edges);
    bp_iter<<<NB, TPB, 0, stream>>>(noise_r, ew, cn_edges, out);
}

// Round 18
// 256.828 us; speedup vs baseline: 1.3177x; 1.3177x over previous
//
#include <hip/hip_runtime.h>
#include <math.h>

#define NV 4096      // variable nodes
#define MC 2048      // check nodes
#define DV 3
#define DC 6
#define NE (NV * DV) // 12288 edges
#define NB 2048      // batch
#define NITER 5
#define TPB 1024     // 16 waves/block; 2 blocks/CU -> 32 waves/CU (HW wave cap)

// Build per-check-node edge lists (slot order arbitrary due to atomics).
__global__ __launch_bounds__(256) void build_cn(const int* __restrict__ cn_idx,
                                                int* __restrict__ cn_edges,
                                                int* __restrict__ cn_cnt) {
    int e = blockIdx.x * 256 + threadIdx.x;
    if (e < NE) {
        int m = cn_idx[e];
        int slot = atomicAdd(&cn_cnt[m], 1);
        cn_edges[m * DC + slot] = e;
    }
}

// Sort each CN's 6 edges ascending (deterministic canonical order; greedy
// input must be canonical so the permutation is launch-invariant).
__global__ __launch_bounds__(256) void sort_cn(int* __restrict__ cn_edges) {
    int m = blockIdx.x * 256 + threadIdx.x;
    if (m < MC) {
        int v[DC];
        for (int j = 0; j < DC; ++j) v[j] = cn_edges[m * DC + j];
        for (int i = 1; i < DC; ++i) {
            int key = v[i]; int j = i - 1;
            while (j >= 0 && v[j] > key) { v[j + 1] = v[j]; --j; }
            v[j + 1] = key;
        }
        for (int j = 0; j < DC; ++j) cn_edges[m * DC + j] = v[j];
    }
}

// Bank-balance the slot assignment (v2: fast). For fixed (c-group, wave,
// slot j), one bp_iter wave instruction reads msg[row[j]] across 64 lanes;
// permuting each row spreads those 64 addresses over the 32 LDS banks.
// R16's version kept counts in LDS (120-cy dependent chain -> 225 us).
// v2: counts live in REGISTER NIBBLES (6 slots x 32 banks x 4 bit = 24
// VGPRs) and each (wave,c) group's 64 lanes split into 4 independent
// 16-lane greedy chunks (128 threads total, ~250 reg-ops/row). Slightly
// lower balance quality than full-serial greedy, ~50x cheaper. Nibble
// overflow (>15 same-bank picks in a 16-row chunk) is ~impossible and
// would only affect quality, not validity. Deterministic; row-local.
__global__ __launch_bounds__(128) void balance_cn(int* __restrict__ cn_edges) {
    const int tid = threadIdx.x;      // 0..127
    const int g   = tid >> 2;         // group 0..31: wave w = g&15, c = g>>4
    const int ct  = tid & 3;          // chunk 0..3 (16 lanes each)
    const int w   = g & 15;
    const int c   = g >> 4;
    const int m0  = c * TPB + w * 64 + ct * 16;   // first CN row of this chunk

    unsigned cnt[DC][4];              // [slot][bank/8] 4-bit counters
#pragma unroll
    for (int j = 0; j < DC; ++j)
#pragma unroll
        for (int q = 0; q < 4; ++q) cnt[j][q] = 0u;

    for (int l = 0; l < 16; ++l) {
        int* row = cn_edges + (m0 + l) * DC;
        int e[DC];
#pragma unroll
        for (int j = 0; j < DC; ++j) e[j] = row[j];

        unsigned used = 0u;
#pragma unroll
        for (int j = 0; j < DC; ++j) {
            int best = -1, bc = 1 << 30, be = 1 << 30;
#pragma unroll
            for (int q = 0; q < DC; ++q) {
                bool valid = ((used >> q) & 1u) == 0u;
                int bank = e[q] & 31;
                int cc = (int)((cnt[j][bank >> 3] >> ((bank & 7) * 4)) & 0xFu);
                bool better = valid && (cc < bc || (cc == bc && e[q] < be));
                if (better) { bc = cc; best = q; be = e[q]; }
            }
            used |= 1u << best;
            int eb = e[best];
            row[j] = eb;
            int bank = eb & 31;
            cnt[j][bank >> 3] += 1u << ((bank & 7) * 4);
        }
    }
}

// bare v_exp_f32 with -|x| folded as input modifier: u = 2^(-|x|)
static __device__ __forceinline__ float exp2_negabs(float x) {
    float r;
    asm volatile("v_exp_f32 %0, -abs(%1)" : "=v"(r) : "v"(x));
    return r;
}
// bare v_log_f32: log2(x)
static __device__ __forceinline__ float log2_raw(float x) {
    float r;
    asm volatile("v_log_f32 %0, %1" : "=v"(r) : "v"(x));
    return r;
}

// R15/R16 structure (one sample/block, 48 KB edge-major LDS, two-phase
// barriers, (1024,8) -> 2 blocks/CU) + log2-domain messages (bare
// v_exp/v_log) + bit-parity sign. CN math [absmax 1.0 proven R13-R16]:
//   u = 2^{-|mw2|}; a = 1+u; b = max(1-u, 1e-12)
//   P = PROD a; M = PROD b  (slot order = bank-balanced permutation)
//   val2_j = log2((P b_j + M a_j) / max(P b_j - M a_j, 2^-23 P b_j))
//            [den floor == ref clip at float32(1-1e-7) = 1-2^-23]
//   sign from bit parity (exact == ref mod-2); final out scaled by ln2.
__global__ __launch_bounds__(TPB, 8) void bp_iter(const float* __restrict__ noise_r,
                                                  const float* __restrict__ ew,
                                                  const int* __restrict__ cn_edges,
                                                  float* __restrict__ out) {
    __shared__ float msg[NE];
    const int b = blockIdx.x;
    const int t = threadIdx.x;

    const float NO    = (float)0.3981071705534972;         // 1/(R*2*10^(EbNo/10))
    const float NSTD  = sqrtf((float)(0.3981071705534972 * 0.5));
    const float LOG2E = 1.4426950408889634f;
    const float LN2   = 0.6931471805599453f;

    // Edge lists of this thread's 2 CNs (loop-invariant, bank-balanced slots).
    int idx[MC / TPB][DC];
#pragma unroll
    for (int c = 0; c < MC / TPB; ++c)
#pragma unroll
        for (int j = 0; j < DC; ++j)
            idx[c][j] = cn_edges[(t + TPB * c) * DC + j];

    float llr2[NV / TPB];   // log2-scaled channel LLRs
    const float* nb = noise_r + (size_t)b * NV;
#pragma unroll
    for (int k = 0; k < NV / TPB; ++k) {
        int n = t + TPB * k;
        float y  = 1.0f + NSTD * nb[n];
        float l2 = ((4.0f * y) / NO) * LOG2E;
        llr2[k] = l2;
        msg[3 * n + 0] = l2 * ew[3 * n + 0];
        msg[3 * n + 1] = l2 * ew[3 * n + 1];
        msg[3 * n + 2] = l2 * ew[3 * n + 2];
    }
    __syncthreads();

    for (int it = 0; it < NITER; ++it) {
        // ---- CN phase: each thread owns 2 check nodes ----
#pragma unroll
        for (int c = 0; c < MC / TPB; ++c) {
            float a[DC], bb[DC];
            unsigned spack = 0u;
#pragma unroll
            for (int j = 0; j < DC; ++j) {
                float mw = msg[idx[c][j]];
                spack |= ((__float_as_uint(mw) >> 31) & 1u) << j;
                float u = exp2_negabs(mw);          // 2^{-|mw2|} = e^{-|mw|}
                a[j]  = 1.0f + u;
                bb[j] = fmaxf(1.0f - u, 1e-12f);
            }
            const unsigned par = __popc(spack) & 1u;

            float P = 1.0f, M = 1.0f;
#pragma unroll
            for (int j = 0; j < DC; ++j) {
                P *= a[j];
                M *= bb[j];
            }

#pragma unroll
            for (int j = 0; j < DC; ++j) {
                float Pb  = P * bb[j];
                float Ma  = M * a[j];
                float num = Pb + Ma;
                float den = fmaxf(Pb - Ma, 0x1.0p-23f * Pb);   // == ref clip 1-2^-23
                float val = log2_raw(__fdividef(num, den));    // >= 0, log2 domain
                msg[idx[c][j]] = __uint_as_float(__float_as_uint(val) |
                                                 (((par ^ (spack >> j)) & 1u) << 31));
            }
        }
        __syncthreads();

        // ---- VN phase: each thread owns 4 variable nodes ----
        if (it < NITER - 1) {
#pragma unroll
            for (int k = 0; k < NV / TPB; ++k) {
                int n = t + TPB * k;
                float c0 = msg[3 * n + 0];
                float c1 = msg[3 * n + 1];
                float c2 = msg[3 * n + 2];
                float tot = llr2[k] + (c0 + c1 + c2);
                msg[3 * n + 0] = (tot - c0) * ew[3 * n + 0];
                msg[3 * n + 1] = (tot - c1) * ew[3 * n + 1];
                msg[3 * n + 2] = (tot - c2) * ew[3 * n + 2];
            }
            __syncthreads();
        } else {
#pragma unroll
            for (int k = 0; k < NV / TPB; ++k) {
                int n = t + TPB * k;
                float c0 = msg[3 * n + 0];
                float c1 = msg[3 * n + 1];
                float c2 = msg[3 * n + 2];
                out[(size_t)b * NV + n] = (llr2[k] + (c0 + c1 + c2)) * LN2;
            }
        }
    }
}

extern "C" void kernel_launch(void* const* d_in, const int* in_sizes, int n_in,
                              void* d_out, int out_size, void* d_ws, size_t ws_size,
                              hipStream_t stream) {
    const float* noise_r = (const float*)d_in[0];
    // d_in[1] = noise_i (unused by reference)
    const float* ew      = (const float*)d_in[2];
    // d_in[3] = vn_idx: known structure e // 3 (edges contiguous per VN)
    const int*   cn_idx  = (const int*)d_in[4];
    float* out = (float*)d_out;

    int* cn_edges = (int*)d_ws;        // NE ints
    int* cn_cnt   = cn_edges + NE;     // MC ints

    hipMemsetAsync(cn_cnt, 0, MC * sizeof(int), stream);
    build_cn<<<(NE + 255) / 256, 256, 0, stream>>>(cn_idx, cn_edges, cn_cnt);
    sort_cn<<<(MC + 255) / 256, 256, 0, stream>>>(cn_edges);
    balance_cn<<<1, 128, 0, stream>>>(cn_edges);
    bp_iter<<<NB, TPB, 0, stream>>>(noise_r, ew, cn_edges, out);
}

// Round 19
// 119.506 us; speedup vs baseline: 2.8318x; 2.1491x over previous
//
#include <hip/hip_runtime.h>
#include <math.h>

#define NV 4096      // variable nodes
#define MC 2048      // check nodes
#define DV 3
#define DC 6
#define NE (NV * DV) // 12288 edges
#define NB 2048      // batch
#define NITER 5
#define TPB 1024     // 16 waves/block; 2 blocks/CU -> 32 waves/CU (HW wave cap)

// Build per-check-node edge lists (slot order arbitrary due to atomics).
__global__ __launch_bounds__(256) void build_cn(const int* __restrict__ cn_idx,
                                                int* __restrict__ cn_edges,
                                                int* __restrict__ cn_cnt) {
    int e = blockIdx.x * 256 + threadIdx.x;
    if (e < NE) {
        int m = cn_idx[e];
        int slot = atomicAdd(&cn_cnt[m], 1);
        cn_edges[m * DC + slot] = e;
    }
}

// Sort each CN's 6 edges ascending -> deterministic, matches ref edge order.
__global__ __launch_bounds__(256) void sort_cn(int* __restrict__ cn_edges) {
    int m = blockIdx.x * 256 + threadIdx.x;
    if (m < MC) {
        int v[DC];
        for (int j = 0; j < DC; ++j) v[j] = cn_edges[m * DC + j];
        for (int i = 1; i < DC; ++i) {
            int key = v[i]; int j = i - 1;
            while (j >= 0 && v[j] > key) { v[j + 1] = v[j]; --j; }
            v[j + 1] = key;
        }
        for (int j = 0; j < DC; ++j) cn_edges[m * DC + j] = v[j];
    }
}

// bare v_exp_f32 with -|x| folded as input modifier: u = 2^(-|x|)
static __device__ __forceinline__ float exp2_negabs(float x) {
    float r;
    asm volatile("v_exp_f32 %0, -abs(%1)" : "=v"(r) : "v"(x));
    return r;
}
// bare v_log_f32: log2(x)
static __device__ __forceinline__ float log2_raw(float x) {
    float r;
    asm volatile("v_log_f32 %0, %1" : "=v"(r) : "v"(x));
    return r;
}

// R15 structure + VECTORIZED VN PHASE. msg layout unchanged (edge-major,
// word 3n+j) so the CN phase and all numerics are byte-identical to R15
// [absmax 1.0 proven]. Change: thread t owns VNs 4t..4t+3, whose 12 words
// are CONTIGUOUS [12t,12t+12) => VN phase = 3x ds_read_b128 + 3x
// ds_write_b128 instead of 24 scalar ds ops (LDS pipe was ~63% of wall;
// b128 moves bytes ~2x faster). Stride-12 b128: each 16-lane quarter hits
// all 32 banks exactly 2x -> 2-way = free (m136). noise/ew/out accesses all
// become float4 (16B/lane coalescing).
// CN math (log2-domain, proven): u = 2^{-|mw2|}; a = 1+u; b = max(1-u,1e-12);
// P = PROD a; M = PROD b; val2 = log2((P b_j + M a_j)/max(P b_j - M a_j,
// 2^-23 P b_j)) [den floor == ref clip float32(1-1e-7) = 1-2^-23]; sign =
// bit parity (exact); out scaled by ln2 once.
__global__ __launch_bounds__(TPB, 8) void bp_iter(const float* __restrict__ noise_r,
                                                  const float* __restrict__ ew,
                                                  const int* __restrict__ cn_edges,
                                                  float* __restrict__ out) {
    __shared__ __align__(16) float msg[NE];
    const int b = blockIdx.x;
    const int t = threadIdx.x;

    const float NO    = (float)0.3981071705534972;         // 1/(R*2*10^(EbNo/10))
    const float NSTD  = sqrtf((float)(0.3981071705534972 * 0.5));
    const float LOG2E = 1.4426950408889634f;
    const float LN2   = 0.6931471805599453f;

    // Edge lists of this thread's 2 CNs (loop-invariant).
    int idx[MC / TPB][DC];
#pragma unroll
    for (int c = 0; c < MC / TPB; ++c)
#pragma unroll
        for (int j = 0; j < DC; ++j)
            idx[c][j] = cn_edges[(t + TPB * c) * DC + j];

    // Edge weights of this thread's 4 VNs (12 contiguous floats, hoisted).
    const float4 w0 = *(const float4*)&ew[12 * t + 0];
    const float4 w1 = *(const float4*)&ew[12 * t + 4];
    const float4 w2 = *(const float4*)&ew[12 * t + 8];

    // Channel LLRs (log2-scaled) for VNs 4t..4t+3.
    const float4 nz = *(const float4*)&noise_r[(size_t)b * NV + 4 * t];
    const float K = (4.0f / NO) * LOG2E;
    float l0 = K * (1.0f + NSTD * nz.x);
    float l1 = K * (1.0f + NSTD * nz.y);
    float l2 = K * (1.0f + NSTD * nz.z);
    float l3 = K * (1.0f + NSTD * nz.w);

    *(float4*)&msg[12 * t + 0] = make_float4(l0 * w0.x, l0 * w0.y, l0 * w0.z, l1 * w0.w);
    *(float4*)&msg[12 * t + 4] = make_float4(l1 * w1.x, l1 * w1.y, l2 * w1.z, l2 * w1.w);
    *(float4*)&msg[12 * t + 8] = make_float4(l2 * w2.x, l3 * w2.y, l3 * w2.z, l3 * w2.w);
    __syncthreads();

    for (int it = 0; it < NITER; ++it) {
        // ---- CN phase: each thread owns 2 check nodes (unchanged R15) ----
#pragma unroll
        for (int c = 0; c < MC / TPB; ++c) {
            float a[DC], bb[DC];
            unsigned spack = 0u;
#pragma unroll
            for (int j = 0; j < DC; ++j) {
                float mw = msg[idx[c][j]];
                spack |= ((__float_as_uint(mw) >> 31) & 1u) << j;
                float u = exp2_negabs(mw);          // 2^{-|mw2|} = e^{-|mw|}
                a[j]  = 1.0f + u;
                bb[j] = fmaxf(1.0f - u, 1e-12f);
            }
            const unsigned par = __popc(spack) & 1u;

            float P = 1.0f, M = 1.0f;
#pragma unroll
            for (int j = 0; j < DC; ++j) {
                P *= a[j];
                M *= bb[j];
            }

#pragma unroll
            for (int j = 0; j < DC; ++j) {
                float Pb  = P * bb[j];
                float Ma  = M * a[j];
                float num = Pb + Ma;
                float den = fmaxf(Pb - Ma, 0x1.0p-23f * Pb);   // == ref clip 1-2^-23
                float val = log2_raw(__fdividef(num, den));    // >= 0, log2 domain
                msg[idx[c][j]] = __uint_as_float(__float_as_uint(val) |
                                                 (((par ^ (spack >> j)) & 1u) << 31));
            }
        }
        __syncthreads();

        // ---- VN phase: 4 contiguous VNs -> 3x b128 read (+3x b128 write) ----
        float4 r0 = *(const float4*)&msg[12 * t + 0];
        float4 r1 = *(const float4*)&msg[12 * t + 4];
        float4 r2 = *(const float4*)&msg[12 * t + 8];
        float tot0 = l0 + ((r0.x + r0.y) + r0.z);
        float tot1 = l1 + ((r0.w + r1.x) + r1.y);
        float tot2 = l2 + ((r1.z + r1.w) + r2.x);
        float tot3 = l3 + ((r2.y + r2.z) + r2.w);

        if (it < NITER - 1) {
            *(float4*)&msg[12 * t + 0] = make_float4((tot0 - r0.x) * w0.x,
                                                     (tot0 - r0.y) * w0.y,
                                                     (tot0 - r0.z) * w0.z,
                                                     (tot1 - r0.w) * w0.w);
            *(float4*)&msg[12 * t + 4] = make_float4((tot1 - r1.x) * w1.x,
                                                     (tot1 - r1.y) * w1.y,
                                                     (tot2 - r1.z) * w1.z,
                                                     (tot2 - r1.w) * w1.w);
            *(float4*)&msg[12 * t + 8] = make_float4((tot2 - r2.x) * w2.x,
                                                     (tot3 - r2.y) * w2.y,
                                                     (tot3 - r2.z) * w2.z,
                                                     (tot3 - r2.w) * w2.w);
            __syncthreads();
        } else {
            *(float4*)&out[(size_t)b * NV + 4 * t] =
                make_float4(tot0 * LN2, tot1 * LN2, tot2 * LN2, tot3 * LN2);
        }
    }
}

extern "C" void kernel_launch(void* const* d_in, const int* in_sizes, int n_in,
                              void* d_out, int out_size, void* d_ws, size_t ws_size,
                              hipStream_t stream) {
    const float* noise_r = (const float*)d_in[0];
    // d_in[1] = noise_i (unused by reference)
    const float* ew      = (const float*)d_in[2];
    // d_in[3] = vn_idx: known structure e // 3 (edges contiguous per VN)
    const int*   cn_idx  = (const int*)d_in[4];
    float* out = (float*)d_out;

    int* cn_edges = (int*)d_ws;        // NE ints
    int* cn_cnt   = cn_edges + NE;     // MC ints

    hipMemsetAsync(cn_cnt, 0, MC * sizeof(int), stream);
    build_cn<<<(NE + 255) / 256, 256, 0, stream>>>(cn_idx, cn_edges, cn_cnt);
    sort_cn<<<(MC + 255) / 256, 256, 0, stream>>>(cn_edges);
    bp_iter<<<NB, TPB, 0, stream>>>(noise_r, ew, cn_edges, out);
}